// Round 2
// baseline (9892.045 us; speedup 1.0000x reference)
//
#include <hip/hip_runtime.h>
#include <hip/hip_bf16.h>
#include <cstdint>

#define T_LEN 512
#define BATCH 128
#define EMBD 256
#define NCLS 25
#define PADTOK 1
#define CHUNK 64
#define NCHUNK 8

#define N_WPERM (2*4*16*8*64*8)   /* 524288 elements, both dirs */
#define N_WE (2*2*8*64*8)         /* 16384 */
#define N_BIAS (2*1024)

typedef float f32x4 __attribute__((ext_vector_type(4)));
typedef short s16x8 __attribute__((ext_vector_type(8)));
typedef unsigned int u32x4 __attribute__((ext_vector_type(4)));

__device__ __forceinline__ unsigned short f2bf(float f) {
  unsigned int u = __builtin_bit_cast(unsigned int, f);
  unsigned int r = (u + 0x7FFFu + ((u >> 16) & 1u)) >> 16;
  return (unsigned short)r;
}
__device__ __forceinline__ float bf2f(unsigned short h) {
  unsigned int u = ((unsigned int)h) << 16;
  return __builtin_bit_cast(float, u);
}

// ---------------- prep: fragment-order weight permutes + bias sum ----------
__global__ void prep_kernel(const float* wih_f, const float* whh_f,
                            const float* bih_f, const float* bhh_f,
                            const float* wih_b, const float* whh_b,
                            const float* bih_b, const float* bhh_b,
                            const float* W_e,
                            unsigned short* wih_p, unsigned short* whh_p,
                            unsigned short* we_p, float* bias)
{
  long total = 2L*N_WPERM + N_WE + N_BIAS;
  for (long i = (long)blockIdx.x*blockDim.x + threadIdx.x; i < total;
       i += (long)gridDim.x*blockDim.x) {
    long j = i;
    if (j < 2L*N_WPERM) {
      int which = (int)(j >> 19);          // 0: w_ih, 1: w_hh
      int o = (int)(j & (N_WPERM-1));
      int e = o & 7, l = (o>>3)&63, kt = (o>>9)&7, s = (o>>12)&15, w = (o>>16)&3, d = (o>>18)&1;
      int gate = s >> 2, sub = s & 3;
      int n = gate*256 + w*64 + sub*16 + (l & 15);
      int k = kt*32 + (l>>4)*8 + e;
      const float* src = which ? (d ? whh_b : whh_f) : (d ? wih_b : wih_f);
      unsigned short* dst = which ? whh_p : wih_p;
      dst[o] = f2bf(src[n*256 + k]);
      continue;
    }
    j -= 2L*N_WPERM;
    if (j < N_WE) {
      int o = (int)j;
      int e = o&7, l = (o>>3)&63, kt = (o>>9)&7, nt = (o>>12)&1, dp = (o>>13)&1;
      int n = nt*16 + (l&15);
      int k = dp*256 + kt*32 + (l>>4)*8 + e;
      we_p[o] = (n < NCLS) ? f2bf(W_e[n*512 + k]) : (unsigned short)0;
      continue;
    }
    j -= N_WE;
    { int o = (int)j; int d = o>>10; int g = o & 1023;
      bias[o] = d ? (bih_b[g]+bhh_b[g]) : (bih_f[g]+bhh_f[g]); }
  }
}

// ------- xg chunk: emb[sent] @ W_ih^T + biases, stored permuted bf16 -------
__global__ __launch_bounds__(256) void xg_kernel(const int* sent, const float* emb,
    const unsigned short* wih_p, const float* bias, unsigned short* xg, int k)
{
  int d = blockIdx.y;
  int blk = blockIdx.x;            // 0..255
  int u = blk >> 2, q = blk & 3;   // u = local step, batch rows 32q..32q+31
  int ss = k*CHUNK + u;
  int t = d ? (T_LEN-1-ss) : ss;
  int w = threadIdx.x >> 6, l = threadIdx.x & 63, lg = l >> 4, lm = l & 15;

  int tok0 = sent[t*BATCH + q*32 + lm];
  int tok1 = sent[t*BATCH + q*32 + 16 + lm];

  f32x4 acc[2][16] = {};
  for (int kt = 0; kt < 8; ++kt) {
    const float* p0 = emb + (long)tok0*256 + kt*32 + lg*8;
    const float* p1 = emb + (long)tok1*256 + kt*32 + lg*8;
    f32x4 q00 = *(const f32x4*)p0, q01 = *(const f32x4*)(p0+4);
    f32x4 q10 = *(const f32x4*)p1, q11 = *(const f32x4*)(p1+4);
    s16x8 a0, a1;
    #pragma unroll
    for (int e = 0; e < 4; ++e) {
      a0[e]   = (short)f2bf(q00[e]); a0[4+e] = (short)f2bf(q01[e]);
      a1[e]   = (short)f2bf(q10[e]); a1[4+e] = (short)f2bf(q11[e]);
    }
    #pragma unroll
    for (int s = 0; s < 16; ++s) {
      long widx = (((long)(d*4 + w)*16 + s)*8 + kt)*64 + l;
      s16x8 bf = *(const s16x8*)((const char*)wih_p + widx*16);
      acc[0][s] = __builtin_amdgcn_mfma_f32_16x16x32_bf16(a0, bf, acc[0][s], 0,0,0);
      acc[1][s] = __builtin_amdgcn_mfma_f32_16x16x32_bf16(a1, bf, acc[1][s], 0,0,0);
    }
  }
  float bsv[16];
  #pragma unroll
  for (int s = 0; s < 16; ++s) {
    int n = (s>>2)*256 + w*64 + (s&3)*16 + lm;
    bsv[s] = bias[d*1024 + n];
  }
  #pragma unroll
  for (int mt = 0; mt < 2; ++mt) {
    int nb = q*2 + mt;
    char* base = (char*)xg + (((((long)d*CHUNK + u)*8 + nb)*4 + w)*64 + l)*128;
    #pragma unroll
    for (int qq = 0; qq < 8; ++qq) {
      u32x4 pk;
      #pragma unroll
      for (int h2 = 0; h2 < 4; ++h2) {
        int j0 = qq*8 + h2*2;
        unsigned short v0 = f2bf(acc[mt][j0>>2][j0&3] + bsv[j0>>2]);
        unsigned short v1 = f2bf(acc[mt][(j0+1)>>2][(j0+1)&3] + bsv[(j0+1)>>2]);
        pk[h2] = (unsigned)v0 | ((unsigned)v1 << 16);
      }
      *(u32x4*)(base + qq*16) = pk;
    }
  }
}

// ---------------- LSTM chunk: recurrence + fused emissions -----------------
__global__ __launch_bounds__(256) void lstm_kernel(const unsigned short* xg,
    const unsigned short* whh_p, const unsigned short* we_p,
    float* emis_f, float* emis_b, unsigned short* hsave, float* csave, int k)
{
  __shared__ alignas(16) unsigned short h_lds[4096];  // [16 rows][256] bf16, XOR-swizzled
  int id = blockIdx.x, d = id >> 3, nb = id & 7, bbase = nb*16;
  int w = threadIdx.x >> 6, l = threadIdx.x & 63, lg = l >> 4, lm = l & 15;
  float* emis = d ? emis_b : emis_f;

  float c[16];
  if (k == 0) {
    for (int i = threadIdx.x; i < 2048; i += 256) ((unsigned*)h_lds)[i] = 0u;
    #pragma unroll
    for (int i = 0; i < 16; ++i) c[i] = 0.f;
  } else {
    u32x4* hl = (u32x4*)h_lds;
    const u32x4* hs = (const u32x4*)(hsave + (long)id*4096);
    for (int i = threadIdx.x; i < 512; i += 256) hl[i] = hs[i];
    const float* cs = csave + ((long)id*256 + threadIdx.x)*16;
    #pragma unroll
    for (int i = 0; i < 16; ++i) c[i] = cs[i];
  }
  __syncthreads();

  int prev_t = (k == 0) ? -1 : (d ? (T_LEN - k*CHUNK) : (k*CHUNK - 1));

  for (int u = 0; u < CHUNK; ++u) {
    int ss = k*CHUNK + u;
    int t = d ? (T_LEN-1-ss) : ss;
    // prefetch this step's xg chunk early
    const char* xbase = (const char*)xg + (((((long)d*CHUNK + u)*8 + nb)*4 + w)*64 + l)*128;
    u32x4 xgc[8];
    #pragma unroll
    for (int qq = 0; qq < 8; ++qq) xgc[qq] = *(const u32x4*)(xbase + qq*16);
    // A-frags of h_{t-1}
    s16x8 a[8];
    #pragma unroll
    for (int kt = 0; kt < 8; ++kt) {
      int off = lm*512 + ((kt*64 + lg*16) ^ ((lm&7)<<4));
      a[kt] = *(const s16x8*)((const char*)h_lds + off);
    }
    __syncthreads();
    // wave 0: emissions for h of previous step (A-frags reused)
    if (w == 0 && prev_t >= 0) {
      #pragma unroll
      for (int nt = 0; nt < 2; ++nt) {
        f32x4 ea = {0.f,0.f,0.f,0.f};
        #pragma unroll
        for (int kt = 0; kt < 8; ++kt) {
          s16x8 bw = *(const s16x8*)((const char*)we_p + ((((long)d*2 + nt)*8 + kt)*64 + l)*16);
          ea = __builtin_amdgcn_mfma_f32_16x16x32_bf16(a[kt], bw, ea, 0,0,0);
        }
        int cc = nt*16 + lm;
        if (cc < NCLS) {
          #pragma unroll
          for (int r = 0; r < 4; ++r)
            emis[((long)prev_t*BATCH + bbase + lg*4 + r)*NCLS + cc] = ea[r];
        }
      }
    }
    // main matvec: gates = h_{t-1} @ W_hh^T  (weights streamed, fragment-ordered)
    f32x4 acc[16];
    #pragma unroll
    for (int s = 0; s < 16; ++s) acc[s] = (f32x4){0.f,0.f,0.f,0.f};
    #pragma unroll
    for (int s = 0; s < 16; ++s) {
      #pragma unroll
      for (int kt = 0; kt < 8; ++kt) {
        s16x8 bw = *(const s16x8*)((const char*)whh_p + (((((long)d*4 + w)*16 + s)*8 + kt)*64 + l)*16);
        acc[s] = __builtin_amdgcn_mfma_f32_16x16x32_bf16(a[kt], bw, acc[s], 0,0,0);
      }
    }
    // add xg
    #pragma unroll
    for (int qq = 0; qq < 8; ++qq) {
      #pragma unroll
      for (int e = 0; e < 8; ++e) {
        int j = qq*8 + e;
        unsigned wd = xgc[qq][e>>1];
        unsigned short us = (e&1) ? (unsigned short)(wd>>16) : (unsigned short)(wd & 0xffff);
        acc[j>>2][j&3] += bf2f(us);
      }
    }
    // nonlinearities: gates i,f,g,o at s = sub, 4+sub, 8+sub, 12+sub
    unsigned short hnew[16];
    #pragma unroll
    for (int sub = 0; sub < 4; ++sub) {
      #pragma unroll
      for (int r = 0; r < 4; ++r) {
        float gi = acc[sub][r],  gf = acc[4+sub][r];
        float gg = acc[8+sub][r], go = acc[12+sub][r];
        float si = 1.f/(1.f+__expf(-gi));
        float sf = 1.f/(1.f+__expf(-gf));
        float so = 1.f/(1.f+__expf(-go));
        float tg = 2.f/(1.f+__expf(-2.f*gg)) - 1.f;
        float cn = sf*c[sub*4+r] + si*tg;
        c[sub*4+r] = cn;
        float tc = 2.f/(1.f+__expf(-2.f*cn)) - 1.f;
        hnew[sub*4+r] = f2bf(so*tc);
      }
    }
    #pragma unroll
    for (int sub = 0; sub < 4; ++sub) {
      #pragma unroll
      for (int r = 0; r < 4; ++r) {
        int m = lg*4 + r;
        int jc = lm + sub*16 + w*64;
        int off = (m*512 + jc*2) ^ ((m&7)<<4);
        *(unsigned short*)((char*)h_lds + off) = hnew[sub*4+r];
      }
    }
    __syncthreads();
    prev_t = t;
  }

  if (k == NCHUNK-1) {
    // emissions for the final h
    if (w == 0) {
      s16x8 a[8];
      #pragma unroll
      for (int kt = 0; kt < 8; ++kt) {
        int off = lm*512 + ((kt*64 + lg*16) ^ ((lm&7)<<4));
        a[kt] = *(const s16x8*)((const char*)h_lds + off);
      }
      #pragma unroll
      for (int nt = 0; nt < 2; ++nt) {
        f32x4 ea = {0.f,0.f,0.f,0.f};
        #pragma unroll
        for (int kt = 0; kt < 8; ++kt) {
          s16x8 bw = *(const s16x8*)((const char*)we_p + ((((long)d*2 + nt)*8 + kt)*64 + l)*16);
          ea = __builtin_amdgcn_mfma_f32_16x16x32_bf16(a[kt], bw, ea, 0,0,0);
        }
        int cc = nt*16 + lm;
        if (cc < NCLS) {
          #pragma unroll
          for (int r = 0; r < 4; ++r)
            emis[((long)prev_t*BATCH + bbase + lg*4 + r)*NCLS + cc] = ea[r];
        }
      }
    }
  } else {
    // save state for next chunk
    u32x4* hl = (u32x4*)h_lds;
    u32x4* hs = (u32x4*)(hsave + (long)id*4096);
    for (int i = threadIdx.x; i < 512; i += 256) hs[i] = hl[i];
    float* cs = csave + ((long)id*256 + threadIdx.x)*16;
    #pragma unroll
    for (int i = 0; i < 16; ++i) cs[i] = c[i];
  }
}

// ---------------- CRF numerator -------------------------------------------
__global__ void num_kernel(const int* sent, const int* tags, const float* emis_f,
    const float* emis_b, const float* b_e, const float* start_t, const float* end_t,
    const float* trans, float* num_buf)
{
  int b = blockIdx.x, l = threadIdx.x;   // 64 threads = 1 wave
  float acc = 0.f; int cnt = 0;
  for (int t = l; t < T_LEN; t += 64) {
    int tag = tags[t*BATCH + b];
    float E = emis_f[((long)t*BATCH+b)*NCLS + tag] + emis_b[((long)t*BATCH+b)*NCLS + tag] + b_e[tag];
    int m = (sent[t*BATCH+b] != PADTOK) ? 1 : 0;
    cnt += m;
    if (t == 0) acc += start_t[tag] + E;
    else if (m) acc += trans[tags[(t-1)*BATCH + b]*NCLS + tag] + E;
  }
  #pragma unroll
  for (int off = 32; off; off >>= 1) { acc += __shfl_xor(acc, off); cnt += __shfl_xor(cnt, off); }
  if (l == 0) num_buf[b] = acc + end_t[tags[(cnt-1)*BATCH + b]];
}

// ---------------- CRF forward algorithm (denominator) ----------------------
__global__ void denom_kernel(const int* sent, const float* emis_f, const float* emis_b,
    const float* b_e, const float* start_t, const float* end_t, const float* trans,
    const float* num_buf, float* llh)
{
  __shared__ float tr[NCLS][32];
  __shared__ float sc[2][32];
  __shared__ float be_s[32];
  int l = threadIdx.x, j = l & 31, h = l >> 5;
  int b = blockIdx.x*2 + h;
  for (int i = l; i < NCLS*32; i += 64) { int r = i >> 5, cj = i & 31; tr[r][cj] = (cj<NCLS)? trans[r*NCLS+cj] : 0.f; }
  if (l < 32) be_s[l] = (l < NCLS) ? b_e[l] : 0.f;
  __syncthreads();
  float score = -1e30f;
  if (j < NCLS) score = start_t[j] + emis_f[(long)b*NCLS+j] + emis_b[(long)b*NCLS+j] + be_s[j];
  for (int t = 1; t < T_LEN; ++t) {
    sc[h][j] = score;
    __syncthreads();
    bool m = sent[t*BATCH + b] != PADTOK;
    float mx = -1e30f;
    for (int i = 0; i < NCLS; ++i) mx = fmaxf(mx, sc[h][i] + tr[i][j]);
    float ssum = 0.f;
    for (int i = 0; i < NCLS; ++i) ssum += __expf(sc[h][i] + tr[i][j] - mx);
    float e = (j < NCLS) ? (emis_f[((long)t*BATCH+b)*NCLS+j] + emis_b[((long)t*BATCH+b)*NCLS+j] + be_s[j]) : 0.f;
    float nxt = mx + __logf(ssum) + e;
    if (m && j < NCLS) score = nxt;
    __syncthreads();
  }
  float v = (j < NCLS) ? score + end_t[j] : -1e30f;
  float mx = v;
  #pragma unroll
  for (int off = 16; off; off >>= 1) mx = fmaxf(mx, __shfl_xor(mx, off));
  float ssum = (j < NCLS) ? __expf(v - mx) : 0.f;
  #pragma unroll
  for (int off = 16; off; off >>= 1) ssum += __shfl_xor(ssum, off);
  if (j == 0) llh[b] = num_buf[b] - (mx + __logf(ssum));
}

__global__ void final_kernel(const float* llh, float* out) {
  __shared__ float red[2];
  int l = threadIdx.x;   // 128
  float v = llh[l];
  #pragma unroll
  for (int off = 32; off; off >>= 1) v += __shfl_xor(v, off);
  if ((l & 63) == 0) red[l >> 6] = v;
  __syncthreads();
  if (l == 0) out[0] = -(red[0] + red[1]);
}

extern "C" void kernel_launch(void* const* d_in, const int* in_sizes, int n_in,
                              void* d_out, int out_size, void* d_ws, size_t ws_size,
                              hipStream_t stream) {
  const int*   sent  = (const int*)d_in[0];
  const int*   tags  = (const int*)d_in[1];
  const float* emb   = (const float*)d_in[2];
  const float* wih_f = (const float*)d_in[3];
  const float* whh_f = (const float*)d_in[4];
  const float* bih_f = (const float*)d_in[5];
  const float* bhh_f = (const float*)d_in[6];
  const float* wih_b = (const float*)d_in[7];
  const float* whh_b = (const float*)d_in[8];
  const float* bih_b = (const float*)d_in[9];
  const float* bhh_b = (const float*)d_in[10];
  const float* W_e   = (const float*)d_in[11];
  const float* b_e   = (const float*)d_in[12];
  const float* st    = (const float*)d_in[13];
  const float* et    = (const float*)d_in[14];
  const float* tr    = (const float*)d_in[15];
  (void)in_sizes; (void)n_in; (void)out_size; (void)ws_size;

  char* ws = (char*)d_ws;
  unsigned short* wih_p  = (unsigned short*)ws; ws += (long)N_WPERM*2;      // 1 MiB
  unsigned short* whh_p  = (unsigned short*)ws; ws += (long)N_WPERM*2;      // 1 MiB
  unsigned short* we_p   = (unsigned short*)ws; ws += (long)N_WE*2;         // 32 KiB
  float*          bias   = (float*)ws;          ws += (long)N_BIAS*4;       // 8 KiB
  unsigned short* xgr    = (unsigned short*)ws; ws += (long)2*CHUNK*BATCH*1024*2; // 32 MiB ring
  float*          emis_f = (float*)ws;          ws += (long)T_LEN*BATCH*NCLS*4;   // 6.25 MiB
  float*          emis_b = (float*)ws;          ws += (long)T_LEN*BATCH*NCLS*4;   // 6.25 MiB
  unsigned short* hsave  = (unsigned short*)ws; ws += (long)16*4096*2;      // 128 KiB
  float*          csave  = (float*)ws;          ws += (long)16*256*16*4;    // 256 KiB
  float*          numb   = (float*)ws;          ws += 512;
  float*          llh    = (float*)ws;          ws += 512;
  // total ~47 MiB

  prep_kernel<<<4168, 256, 0, stream>>>(wih_f, whh_f, bih_f, bhh_f,
                                        wih_b, whh_b, bih_b, bhh_b, W_e,
                                        wih_p, whh_p, we_p, bias);
  for (int k = 0; k < NCHUNK; ++k) {
    dim3 g1(256, 2);
    xg_kernel<<<g1, 256, 0, stream>>>(sent, emb, wih_p, bias, xgr, k);
    lstm_kernel<<<16, 256, 0, stream>>>(xgr, whh_p, we_p, emis_f, emis_b, hsave, csave, k);
  }
  num_kernel<<<128, 64, 0, stream>>>(sent, tags, emis_f, emis_b, b_e, st, et, tr, numb);
  denom_kernel<<<64, 64, 0, stream>>>(sent, emis_f, emis_b, b_e, st, et, tr, numb, llh);
  final_kernel<<<1, 128, 0, stream>>>(llh, (float*)d_out);
}

// Round 3
// 9125.795 us; speedup vs baseline: 1.0840x; 1.0840x over previous
//
#include <hip/hip_runtime.h>
#include <hip/hip_bf16.h>
#include <cstdint>

#define T_LEN 512
#define BATCH 128
#define EMBD 256
#define NCLS 25
#define PADTOK 1
#define CHUNK 64
#define NCHUNK 8

#define N_WPERM (2*4*16*8*64*8)   /* 524288 elements, both dirs */
#define N_WE (2*2*8*64*8)         /* 16384 */
#define N_BIAS (2*1024)

typedef float f32x4 __attribute__((ext_vector_type(4)));
typedef short s16x8 __attribute__((ext_vector_type(8)));
typedef unsigned int u32x4 __attribute__((ext_vector_type(4)));

__device__ __forceinline__ unsigned short f2bf(float f) {
  unsigned int u = __builtin_bit_cast(unsigned int, f);
  unsigned int r = (u + 0x7FFFu + ((u >> 16) & 1u)) >> 16;
  return (unsigned short)r;
}
__device__ __forceinline__ float bf2f(unsigned short h) {
  unsigned int u = ((unsigned int)h) << 16;
  return __builtin_bit_cast(float, u);
}

// ---------------- prep: fragment-order weight permutes + bias sum ----------
// weight layout: o = (((((d*4+w)*8 + kt)*16 + s)*64 + l)*8 + e)
__global__ void prep_kernel(const float* wih_f, const float* whh_f,
                            const float* bih_f, const float* bhh_f,
                            const float* wih_b, const float* whh_b,
                            const float* bih_b, const float* bhh_b,
                            const float* W_e,
                            unsigned short* wih_p, unsigned short* whh_p,
                            unsigned short* we_p, float* bias)
{
  long total = 2L*N_WPERM + N_WE + N_BIAS;
  for (long i = (long)blockIdx.x*blockDim.x + threadIdx.x; i < total;
       i += (long)gridDim.x*blockDim.x) {
    long j = i;
    if (j < 2L*N_WPERM) {
      int which = (int)(j >> 19);          // 0: w_ih, 1: w_hh
      int o = (int)(j & (N_WPERM-1));
      int e = o & 7, l = (o>>3)&63, s = (o>>9)&15, kt = (o>>13)&7, w = (o>>16)&3, d = (o>>18)&1;
      int gate = s >> 2, sub = s & 3;
      int n = gate*256 + w*64 + sub*16 + (l & 15);
      int k = kt*32 + (l>>4)*8 + e;
      const float* src = which ? (d ? whh_b : whh_f) : (d ? wih_b : wih_f);
      unsigned short* dst = which ? whh_p : wih_p;
      dst[o] = f2bf(src[n*256 + k]);
      continue;
    }
    j -= 2L*N_WPERM;
    if (j < N_WE) {
      int o = (int)j;
      int e = o&7, l = (o>>3)&63, kt = (o>>9)&7, nt = (o>>12)&1, dp = (o>>13)&1;
      int n = nt*16 + (l&15);
      int k = dp*256 + kt*32 + (l>>4)*8 + e;
      we_p[o] = (n < NCLS) ? f2bf(W_e[n*512 + k]) : (unsigned short)0;
      continue;
    }
    j -= N_WE;
    { int o = (int)j; int d = o>>10; int g = o & 1023;
      bias[o] = d ? (bih_b[g]+bhh_b[g]) : (bih_f[g]+bhh_f[g]); }
  }
}

// ------- xg chunk: emb[sent] @ W_ih^T + biases, stored permuted bf16 -------
__global__ __launch_bounds__(256) void xg_kernel(const int* sent, const float* emb,
    const unsigned short* wih_p, const float* bias, unsigned short* xg, int k)
{
  int d = blockIdx.y;
  int blk = blockIdx.x;            // 0..255
  int u = blk >> 2, q = blk & 3;   // u = local step, batch rows 32q..32q+31
  int ss = k*CHUNK + u;
  int t = d ? (T_LEN-1-ss) : ss;
  int w = threadIdx.x >> 6, l = threadIdx.x & 63, lg = l >> 4, lm = l & 15;

  int tok0 = sent[t*BATCH + q*32 + lm];
  int tok1 = sent[t*BATCH + q*32 + 16 + lm];

  const char* wbase = (const char*)wih_p + ((long)(d*4 + w) << 17);

  f32x4 acc[2][16] = {};
  for (int kt = 0; kt < 8; ++kt) {
    const float* p0 = emb + (long)tok0*256 + kt*32 + lg*8;
    const float* p1 = emb + (long)tok1*256 + kt*32 + lg*8;
    f32x4 q00 = *(const f32x4*)p0, q01 = *(const f32x4*)(p0+4);
    f32x4 q10 = *(const f32x4*)p1, q11 = *(const f32x4*)(p1+4);
    s16x8 a0, a1;
    #pragma unroll
    for (int e = 0; e < 4; ++e) {
      a0[e]   = (short)f2bf(q00[e]); a0[4+e] = (short)f2bf(q01[e]);
      a1[e]   = (short)f2bf(q10[e]); a1[4+e] = (short)f2bf(q11[e]);
    }
    #pragma unroll
    for (int s = 0; s < 16; ++s) {
      s16x8 bf = *(const s16x8*)(wbase + (((kt*16 + s) << 10) + (l << 4)));
      acc[0][s] = __builtin_amdgcn_mfma_f32_16x16x32_bf16(a0, bf, acc[0][s], 0,0,0);
      acc[1][s] = __builtin_amdgcn_mfma_f32_16x16x32_bf16(a1, bf, acc[1][s], 0,0,0);
    }
  }
  float bsv[16];
  #pragma unroll
  for (int s = 0; s < 16; ++s) {
    int n = (s>>2)*256 + w*64 + (s&3)*16 + lm;
    bsv[s] = bias[d*1024 + n];
  }
  #pragma unroll
  for (int mt = 0; mt < 2; ++mt) {
    int nb = q*2 + mt;
    char* base = (char*)xg + (((((long)d*CHUNK + u)*8 + nb)*4 + w)*64 + l)*128;
    #pragma unroll
    for (int qq = 0; qq < 8; ++qq) {
      u32x4 pk;
      #pragma unroll
      for (int h2 = 0; h2 < 4; ++h2) {
        int j0 = qq*8 + h2*2;
        unsigned short v0 = f2bf(acc[mt][j0>>2][j0&3] + bsv[j0>>2]);
        unsigned short v1 = f2bf(acc[mt][(j0+1)>>2][(j0+1)&3] + bsv[(j0+1)>>2]);
        pk[h2] = (unsigned)v0 | ((unsigned)v1 << 16);
      }
      *(u32x4*)(base + qq*16) = pk;
    }
  }
}

// ---------------- LSTM chunk: recurrence + fused emissions -----------------
__global__ __launch_bounds__(256, 1) void lstm_kernel(const unsigned short* xg,
    const unsigned short* whh_p, const unsigned short* we_p,
    float* emis_f, float* emis_b, unsigned short* hsave, float* csave, int k)
{
  __shared__ alignas(16) unsigned short h_lds[4096];  // [16 rows][256] bf16, XOR-swizzled
  int id = blockIdx.x, d = id >> 3, nb = id & 7, bbase = nb*16;
  int w = threadIdx.x >> 6, l = threadIdx.x & 63, lg = l >> 4, lm = l & 15;
  float* emis = d ? emis_b : emis_f;

  const char* wbase = (const char*)whh_p + ((long)(d*4 + w) << 17);

  // emissions weights hoisted to registers; waves 0,1 own nt = w
  s16x8 ewreg[8];
  if (w < 2) {
    #pragma unroll
    for (int kt = 0; kt < 8; ++kt)
      ewreg[kt] = *(const s16x8*)((const char*)we_p + ((((long)d*2 + w)*8 + kt)*64 + l)*16);
  }

  float c[16];
  if (k == 0) {
    for (int i = threadIdx.x; i < 2048; i += 256) ((unsigned*)h_lds)[i] = 0u;
    #pragma unroll
    for (int i = 0; i < 16; ++i) c[i] = 0.f;
  } else {
    u32x4* hl = (u32x4*)h_lds;
    const u32x4* hs = (const u32x4*)(hsave + (long)id*4096);
    for (int i = threadIdx.x; i < 512; i += 256) hl[i] = hs[i];
    const float* cs = csave + ((long)id*256 + threadIdx.x)*16;
    #pragma unroll
    for (int i = 0; i < 16; ++i) c[i] = cs[i];
  }
  __syncthreads();

  int prev_t = (k == 0) ? -1 : (d ? (T_LEN - k*CHUNK) : (k*CHUNK - 1));

  for (int u = 0; u < CHUNK; ++u) {
    int ss = k*CHUNK + u;
    int t = d ? (T_LEN-1-ss) : ss;
    // prefetch this step's xg chunk early (HBM latency hides under weight pipeline)
    const char* xbase = (const char*)xg + (((((long)d*CHUNK + u)*8 + nb)*4 + w)*64 + l)*128;
    u32x4 xgc[8];
    #pragma unroll
    for (int qq = 0; qq < 8; ++qq) xgc[qq] = *(const u32x4*)(xbase + qq*16);
    // A-frags of h_{t-1}
    s16x8 a[8];
    #pragma unroll
    for (int kt = 0; kt < 8; ++kt) {
      int off = lm*512 + ((kt*64 + lg*16) ^ ((lm&7)<<4));
      a[kt] = *(const s16x8*)((const char*)h_lds + off);
    }
    __syncthreads();
    // waves 0,1: emissions for h of previous step (A-frags + hoisted weights)
    if (w < 2 && prev_t >= 0) {
      f32x4 ea = {0.f,0.f,0.f,0.f};
      #pragma unroll
      for (int kt = 0; kt < 8; ++kt)
        ea = __builtin_amdgcn_mfma_f32_16x16x32_bf16(a[kt], ewreg[kt], ea, 0,0,0);
      int cc = w*16 + lm;
      if (cc < NCLS) {
        #pragma unroll
        for (int r = 0; r < 4; ++r)
          emis[((long)prev_t*BATCH + bbase + lg*4 + r)*NCLS + cc] = ea[r];
      }
    }
    // main matvec: gates = h_{t-1} @ W_hh^T
    // software-pipelined: 16-load kt-groups double-buffered in registers
    f32x4 acc[16];
    #pragma unroll
    for (int s = 0; s < 16; ++s) acc[s] = (f32x4){0.f,0.f,0.f,0.f};
    s16x8 wbuf[2][16];
    #pragma unroll
    for (int s = 0; s < 16; ++s)
      wbuf[0][s] = *(const s16x8*)(wbase + ((s << 10) + (l << 4)));
    #pragma unroll
    for (int kt = 0; kt < 8; ++kt) {
      if (kt < 7) {
        #pragma unroll
        for (int s = 0; s < 16; ++s)
          wbuf[(kt+1)&1][s] = *(const s16x8*)(wbase + ((((kt+1)*16 + s) << 10) + (l << 4)));
      }
      #pragma unroll
      for (int s = 0; s < 16; ++s)
        acc[s] = __builtin_amdgcn_mfma_f32_16x16x32_bf16(a[kt], wbuf[kt&1][s], acc[s], 0,0,0);
    }
    // add xg
    #pragma unroll
    for (int qq = 0; qq < 8; ++qq) {
      #pragma unroll
      for (int e = 0; e < 8; ++e) {
        int j = qq*8 + e;
        unsigned wd = xgc[qq][e>>1];
        unsigned short us = (e&1) ? (unsigned short)(wd>>16) : (unsigned short)(wd & 0xffff);
        acc[j>>2][j&3] += bf2f(us);
      }
    }
    // nonlinearities: gates i,f,g,o at s = sub, 4+sub, 8+sub, 12+sub
    unsigned short hnew[16];
    #pragma unroll
    for (int sub = 0; sub < 4; ++sub) {
      #pragma unroll
      for (int r = 0; r < 4; ++r) {
        float gi = acc[sub][r],  gf = acc[4+sub][r];
        float gg = acc[8+sub][r], go = acc[12+sub][r];
        float si = 1.f/(1.f+__expf(-gi));
        float sf = 1.f/(1.f+__expf(-gf));
        float so = 1.f/(1.f+__expf(-go));
        float tg = 2.f/(1.f+__expf(-2.f*gg)) - 1.f;
        float cn = sf*c[sub*4+r] + si*tg;
        c[sub*4+r] = cn;
        float tc = 2.f/(1.f+__expf(-2.f*cn)) - 1.f;
        hnew[sub*4+r] = f2bf(so*tc);
      }
    }
    #pragma unroll
    for (int sub = 0; sub < 4; ++sub) {
      #pragma unroll
      for (int r = 0; r < 4; ++r) {
        int m = lg*4 + r;
        int jc = lm + sub*16 + w*64;
        int off = (m*512 + jc*2) ^ ((m&7)<<4);
        *(unsigned short*)((char*)h_lds + off) = hnew[sub*4+r];
      }
    }
    __syncthreads();
    prev_t = t;
  }

  if (k == NCHUNK-1) {
    // emissions for the final h
    if (w < 2) {
      s16x8 a[8];
      #pragma unroll
      for (int kt = 0; kt < 8; ++kt) {
        int off = lm*512 + ((kt*64 + lg*16) ^ ((lm&7)<<4));
        a[kt] = *(const s16x8*)((const char*)h_lds + off);
      }
      f32x4 ea = {0.f,0.f,0.f,0.f};
      #pragma unroll
      for (int kt = 0; kt < 8; ++kt)
        ea = __builtin_amdgcn_mfma_f32_16x16x32_bf16(a[kt], ewreg[kt], ea, 0,0,0);
      int cc = w*16 + lm;
      if (cc < NCLS) {
        #pragma unroll
        for (int r = 0; r < 4; ++r)
          emis[((long)prev_t*BATCH + bbase + lg*4 + r)*NCLS + cc] = ea[r];
      }
    }
  } else {
    // save state for next chunk
    u32x4* hl = (u32x4*)h_lds;
    u32x4* hs = (u32x4*)(hsave + (long)id*4096);
    for (int i = threadIdx.x; i < 512; i += 256) hs[i] = hl[i];
    float* cs = csave + ((long)id*256 + threadIdx.x)*16;
    #pragma unroll
    for (int i = 0; i < 16; ++i) cs[i] = c[i];
  }
}

// ---------------- CRF numerator -------------------------------------------
__global__ void num_kernel(const int* sent, const int* tags, const float* emis_f,
    const float* emis_b, const float* b_e, const float* start_t, const float* end_t,
    const float* trans, float* num_buf)
{
  int b = blockIdx.x, l = threadIdx.x;   // 64 threads = 1 wave
  float acc = 0.f; int cnt = 0;
  for (int t = l; t < T_LEN; t += 64) {
    int tag = tags[t*BATCH + b];
    float E = emis_f[((long)t*BATCH+b)*NCLS + tag] + emis_b[((long)t*BATCH+b)*NCLS + tag] + b_e[tag];
    int m = (sent[t*BATCH+b] != PADTOK) ? 1 : 0;
    cnt += m;
    if (t == 0) acc += start_t[tag] + E;
    else if (m) acc += trans[tags[(t-1)*BATCH + b]*NCLS + tag] + E;
  }
  #pragma unroll
  for (int off = 32; off; off >>= 1) { acc += __shfl_xor(acc, off); cnt += __shfl_xor(cnt, off); }
  if (l == 0) num_buf[b] = acc + end_t[tags[(cnt-1)*BATCH + b]];
}

// ---------------- CRF forward algorithm (denominator) ----------------------
__global__ void denom_kernel(const int* sent, const float* emis_f, const float* emis_b,
    const float* b_e, const float* start_t, const float* end_t, const float* trans,
    const float* num_buf, float* llh)
{
  __shared__ float tr[NCLS][32];
  __shared__ float sc[2][32];
  __shared__ float be_s[32];
  int l = threadIdx.x, j = l & 31, h = l >> 5;
  int b = blockIdx.x*2 + h;
  for (int i = l; i < NCLS*32; i += 64) { int r = i >> 5, cj = i & 31; tr[r][cj] = (cj<NCLS)? trans[r*NCLS+cj] : 0.f; }
  if (l < 32) be_s[l] = (l < NCLS) ? b_e[l] : 0.f;
  __syncthreads();
  float score = -1e30f;
  if (j < NCLS) score = start_t[j] + emis_f[(long)b*NCLS+j] + emis_b[(long)b*NCLS+j] + be_s[j];
  for (int t = 1; t < T_LEN; ++t) {
    sc[h][j] = score;
    __syncthreads();
    bool m = sent[t*BATCH + b] != PADTOK;
    float mx = -1e30f;
    for (int i = 0; i < NCLS; ++i) mx = fmaxf(mx, sc[h][i] + tr[i][j]);
    float ssum = 0.f;
    for (int i = 0; i < NCLS; ++i) ssum += __expf(sc[h][i] + tr[i][j] - mx);
    float e = (j < NCLS) ? (emis_f[((long)t*BATCH+b)*NCLS+j] + emis_b[((long)t*BATCH+b)*NCLS+j] + be_s[j]) : 0.f;
    float nxt = mx + __logf(ssum) + e;
    if (m && j < NCLS) score = nxt;
    __syncthreads();
  }
  float v = (j < NCLS) ? score + end_t[j] : -1e30f;
  float mx = v;
  #pragma unroll
  for (int off = 16; off; off >>= 1) mx = fmaxf(mx, __shfl_xor(mx, off));
  float ssum = (j < NCLS) ? __expf(v - mx) : 0.f;
  #pragma unroll
  for (int off = 16; off; off >>= 1) ssum += __shfl_xor(ssum, off);
  if (j == 0) llh[b] = num_buf[b] - (mx + __logf(ssum));
}

__global__ void final_kernel(const float* llh, float* out) {
  __shared__ float red[2];
  int l = threadIdx.x;   // 128
  float v = llh[l];
  #pragma unroll
  for (int off = 32; off; off >>= 1) v += __shfl_xor(v, off);
  if ((l & 63) == 0) red[l >> 6] = v;
  __syncthreads();
  if (l == 0) out[0] = -(red[0] + red[1]);
}

extern "C" void kernel_launch(void* const* d_in, const int* in_sizes, int n_in,
                              void* d_out, int out_size, void* d_ws, size_t ws_size,
                              hipStream_t stream) {
  const int*   sent  = (const int*)d_in[0];
  const int*   tags  = (const int*)d_in[1];
  const float* emb   = (const float*)d_in[2];
  const float* wih_f = (const float*)d_in[3];
  const float* whh_f = (const float*)d_in[4];
  const float* bih_f = (const float*)d_in[5];
  const float* bhh_f = (const float*)d_in[6];
  const float* wih_b = (const float*)d_in[7];
  const float* whh_b = (const float*)d_in[8];
  const float* bih_b = (const float*)d_in[9];
  const float* bhh_b = (const float*)d_in[10];
  const float* W_e   = (const float*)d_in[11];
  const float* b_e   = (const float*)d_in[12];
  const float* st    = (const float*)d_in[13];
  const float* et    = (const float*)d_in[14];
  const float* tr    = (const float*)d_in[15];
  (void)in_sizes; (void)n_in; (void)out_size; (void)ws_size;

  char* ws = (char*)d_ws;
  unsigned short* wih_p  = (unsigned short*)ws; ws += (long)N_WPERM*2;      // 1 MiB
  unsigned short* whh_p  = (unsigned short*)ws; ws += (long)N_WPERM*2;      // 1 MiB
  unsigned short* we_p   = (unsigned short*)ws; ws += (long)N_WE*2;         // 32 KiB
  float*          bias   = (float*)ws;          ws += (long)N_BIAS*4;       // 8 KiB
  unsigned short* xgr    = (unsigned short*)ws; ws += (long)2*CHUNK*BATCH*1024*2; // 32 MiB ring
  float*          emis_f = (float*)ws;          ws += (long)T_LEN*BATCH*NCLS*4;   // 6.25 MiB
  float*          emis_b = (float*)ws;          ws += (long)T_LEN*BATCH*NCLS*4;   // 6.25 MiB
  unsigned short* hsave  = (unsigned short*)ws; ws += (long)16*4096*2;      // 128 KiB
  float*          csave  = (float*)ws;          ws += (long)16*256*16*4;    // 256 KiB
  float*          numb   = (float*)ws;          ws += 512;
  float*          llh    = (float*)ws;          ws += 512;
  // total ~47 MiB

  prep_kernel<<<4168, 256, 0, stream>>>(wih_f, whh_f, bih_f, bhh_f,
                                        wih_b, whh_b, bih_b, bhh_b, W_e,
                                        wih_p, whh_p, we_p, bias);
  for (int k = 0; k < NCHUNK; ++k) {
    dim3 g1(256, 2);
    xg_kernel<<<g1, 256, 0, stream>>>(sent, emb, wih_p, bias, xgr, k);
    lstm_kernel<<<16, 256, 0, stream>>>(xgr, whh_p, we_p, emis_f, emis_b, hsave, csave, k);
  }
  num_kernel<<<128, 64, 0, stream>>>(sent, tags, emis_f, emis_b, b_e, st, et, tr, numb);
  denom_kernel<<<64, 64, 0, stream>>>(sent, emis_f, emis_b, b_e, st, et, tr, numb, llh);
  final_kernel<<<1, 128, 0, stream>>>(llh, (float*)d_out);
}

// Round 4
// 5538.863 us; speedup vs baseline: 1.7859x; 1.6476x over previous
//
#include <hip/hip_runtime.h>
#include <hip/hip_bf16.h>
#include <cstdint>

#define T_LEN 512
#define BATCH 128
#define EMBD 256
#define NCLS 25
#define PADTOK 1
#define CHUNK 64
#define NCHUNK 8

#define N_WPERM (2*4*16*8*64*8)   /* 524288 elements, both dirs */
#define N_WE (2*2*8*64*8)         /* 16384 */
#define N_BIAS (2*1024)

// dynamic LDS: 8 KB h + 4 waves * 2 bufs * 16 KB weight stage = 136 KB
#define LDS_BYTES (8192 + 4*2*16384)

typedef float f32x4 __attribute__((ext_vector_type(4)));
typedef short s16x8 __attribute__((ext_vector_type(8)));
typedef unsigned int u32x4 __attribute__((ext_vector_type(4)));

__device__ __forceinline__ unsigned short f2bf(float f) {
  unsigned int u = __builtin_bit_cast(unsigned int, f);
  unsigned int r = (u + 0x7FFFu + ((u >> 16) & 1u)) >> 16;
  return (unsigned short)r;
}
__device__ __forceinline__ float bf2f(unsigned short h) {
  unsigned int u = ((unsigned int)h) << 16;
  return __builtin_bit_cast(float, u);
}
// async global->LDS, 16 B per lane; LDS dest is wave-uniform base + lane*16
__device__ __forceinline__ void gll16(const void* g, void* l) {
  __builtin_amdgcn_global_load_lds(
      (const __attribute__((address_space(1))) unsigned int*)g,
      (__attribute__((address_space(3))) unsigned int*)l, 16, 0, 0);
}

// ---------------- prep: fragment-order weight permutes + bias sum ----------
// weight layout: o = (((((d*4+w)*8 + kt)*16 + s)*64 + l)*8 + e)
__global__ void prep_kernel(const float* wih_f, const float* whh_f,
                            const float* bih_f, const float* bhh_f,
                            const float* wih_b, const float* whh_b,
                            const float* bih_b, const float* bhh_b,
                            const float* W_e,
                            unsigned short* wih_p, unsigned short* whh_p,
                            unsigned short* we_p, float* bias)
{
  long total = 2L*N_WPERM + N_WE + N_BIAS;
  for (long i = (long)blockIdx.x*blockDim.x + threadIdx.x; i < total;
       i += (long)gridDim.x*blockDim.x) {
    long j = i;
    if (j < 2L*N_WPERM) {
      int which = (int)(j >> 19);          // 0: w_ih, 1: w_hh
      int o = (int)(j & (N_WPERM-1));
      int e = o & 7, l = (o>>3)&63, s = (o>>9)&15, kt = (o>>13)&7, w = (o>>16)&3, d = (o>>18)&1;
      int gate = s >> 2, sub = s & 3;
      int n = gate*256 + w*64 + sub*16 + (l & 15);
      int k = kt*32 + (l>>4)*8 + e;
      const float* src = which ? (d ? whh_b : whh_f) : (d ? wih_b : wih_f);
      unsigned short* dst = which ? whh_p : wih_p;
      dst[o] = f2bf(src[n*256 + k]);
      continue;
    }
    j -= 2L*N_WPERM;
    if (j < N_WE) {
      int o = (int)j;
      int e = o&7, l = (o>>3)&63, kt = (o>>9)&7, nt = (o>>12)&1, dp = (o>>13)&1;
      int n = nt*16 + (l&15);
      int k = dp*256 + kt*32 + (l>>4)*8 + e;
      we_p[o] = (n < NCLS) ? f2bf(W_e[n*512 + k]) : (unsigned short)0;
      continue;
    }
    j -= N_WE;
    { int o = (int)j; int d = o>>10; int g = o & 1023;
      bias[o] = d ? (bih_b[g]+bhh_b[g]) : (bih_f[g]+bhh_f[g]); }
  }
}

// ------- xg chunk: emb[sent] @ W_ih^T + biases, stored permuted bf16 -------
__global__ __launch_bounds__(256) void xg_kernel(const int* sent, const float* emb,
    const unsigned short* wih_p, const float* bias, unsigned short* xg, int k)
{
  int d = blockIdx.y;
  int blk = blockIdx.x;            // 0..255
  int u = blk >> 2, q = blk & 3;   // u = local step, batch rows 32q..32q+31
  int ss = k*CHUNK + u;
  int t = d ? (T_LEN-1-ss) : ss;
  int w = threadIdx.x >> 6, l = threadIdx.x & 63, lg = l >> 4, lm = l & 15;

  int tok0 = sent[t*BATCH + q*32 + lm];
  int tok1 = sent[t*BATCH + q*32 + 16 + lm];

  const char* wbase = (const char*)wih_p + ((long)(d*4 + w) << 17);

  f32x4 acc[2][16] = {};
  for (int kt = 0; kt < 8; ++kt) {
    const float* p0 = emb + (long)tok0*256 + kt*32 + lg*8;
    const float* p1 = emb + (long)tok1*256 + kt*32 + lg*8;
    f32x4 q00 = *(const f32x4*)p0, q01 = *(const f32x4*)(p0+4);
    f32x4 q10 = *(const f32x4*)p1, q11 = *(const f32x4*)(p1+4);
    s16x8 a0, a1;
    #pragma unroll
    for (int e = 0; e < 4; ++e) {
      a0[e]   = (short)f2bf(q00[e]); a0[4+e] = (short)f2bf(q01[e]);
      a1[e]   = (short)f2bf(q10[e]); a1[4+e] = (short)f2bf(q11[e]);
    }
    #pragma unroll
    for (int s = 0; s < 16; ++s) {
      s16x8 bf = *(const s16x8*)(wbase + (((kt*16 + s) << 10) + (l << 4)));
      acc[0][s] = __builtin_amdgcn_mfma_f32_16x16x32_bf16(a0, bf, acc[0][s], 0,0,0);
      acc[1][s] = __builtin_amdgcn_mfma_f32_16x16x32_bf16(a1, bf, acc[1][s], 0,0,0);
    }
  }
  float bsv[16];
  #pragma unroll
  for (int s = 0; s < 16; ++s) {
    int n = (s>>2)*256 + w*64 + (s&3)*16 + lm;
    bsv[s] = bias[d*1024 + n];
  }
  #pragma unroll
  for (int mt = 0; mt < 2; ++mt) {
    int nb = q*2 + mt;
    char* base = (char*)xg + (((((long)d*CHUNK + u)*8 + nb)*4 + w)*64 + l)*128;
    #pragma unroll
    for (int qq = 0; qq < 8; ++qq) {
      u32x4 pk;
      #pragma unroll
      for (int h2 = 0; h2 < 4; ++h2) {
        int j0 = qq*8 + h2*2;
        unsigned short v0 = f2bf(acc[mt][j0>>2][j0&3] + bsv[j0>>2]);
        unsigned short v1 = f2bf(acc[mt][(j0+1)>>2][(j0+1)&3] + bsv[(j0+1)>>2]);
        pk[h2] = (unsigned)v0 | ((unsigned)v1 << 16);
      }
      *(u32x4*)(base + qq*16) = pk;
    }
  }
}

// ---------------- LSTM chunk: recurrence + fused emissions -----------------
// Weights stream global->LDS via global_load_lds, double-buffered per wave,
// counted vmcnt (never drained mid-loop), no barriers in the weight pipeline.
__global__ __launch_bounds__(256, 1) void lstm_kernel(const unsigned short* xg,
    const unsigned short* whh_p, const unsigned short* we_p,
    float* emis_f, float* emis_b, unsigned short* hsave, float* csave, int k)
{
  extern __shared__ char smem[];
  unsigned short* h_lds = (unsigned short*)smem;       // 8 KB, XOR-swizzled
  char* wlds = smem + 8192 + (threadIdx.x >> 6)*32768; // per-wave 2 x 16 KB

  int id = blockIdx.x, d = id >> 3, nb = id & 7, bbase = nb*16;
  int w = threadIdx.x >> 6, l = threadIdx.x & 63, lg = l >> 4, lm = l & 15;
  float* emis = d ? emis_b : emis_f;

  const char* wbase = (const char*)whh_p + ((long)(d*4 + w) << 17);

  // emissions weights hoisted to registers; waves 0,1 own nt = w
  s16x8 ewreg[8];
  if (w < 2) {
    #pragma unroll
    for (int kt = 0; kt < 8; ++kt)
      ewreg[kt] = *(const s16x8*)((const char*)we_p + ((((long)d*2 + w)*8 + kt)*64 + l)*16);
  }

  float c[16];
  if (k == 0) {
    for (int i = threadIdx.x; i < 2048; i += 256) ((unsigned*)h_lds)[i] = 0u;
    #pragma unroll
    for (int i = 0; i < 16; ++i) c[i] = 0.f;
  } else {
    u32x4* hl = (u32x4*)h_lds;
    const u32x4* hs = (const u32x4*)(hsave + (long)id*4096);
    for (int i = threadIdx.x; i < 512; i += 256) hl[i] = hs[i];
    const float* cs = csave + ((long)id*256 + threadIdx.x)*16;
    #pragma unroll
    for (int i = 0; i < 16; ++i) c[i] = cs[i];
  }
  __syncthreads();

  int prev_t = (k == 0) ? -1 : (d ? (T_LEN - k*CHUNK) : (k*CHUNK - 1));

  for (int u = 0; u < CHUNK; ++u) {
    int ss = k*CHUNK + u;
    int t = d ? (T_LEN-1-ss) : ss;
    // A-frags of h_{t-1}
    s16x8 a[8];
    #pragma unroll
    for (int kt = 0; kt < 8; ++kt) {
      int off = lm*512 + ((kt*64 + lg*16) ^ ((lm&7)<<4));
      a[kt] = *(const s16x8*)((const char*)h_lds + off);
    }
    __syncthreads();   // readers done before writers; vm outstanding == 0 here

    // issue xg loads (oldest in vm queue)
    const char* xbase = (const char*)xg + (((((long)d*CHUNK + u)*8 + nb)*4 + w)*64 + l)*128;
    u32x4 xgc[8];
    #pragma unroll
    for (int qq = 0; qq < 8; ++qq) xgc[qq] = *(const u32x4*)(xbase + qq*16);
    // issue weight batches 0 and 1 (16 frags each) into LDS double buffer
    #pragma unroll
    for (int s = 0; s < 16; ++s)
      gll16(wbase + (s << 10) + (l << 4), wlds + (s << 10));
    #pragma unroll
    for (int s = 0; s < 16; ++s)
      gll16(wbase + ((16 + s) << 10) + (l << 4), wlds + 16384 + (s << 10));

    // waves 0,1: emissions for previous h, overlapped with gll latency
    if (w < 2 && prev_t >= 0) {
      f32x4 ea = {0.f,0.f,0.f,0.f};
      #pragma unroll
      for (int kt = 0; kt < 8; ++kt)
        ea = __builtin_amdgcn_mfma_f32_16x16x32_bf16(a[kt], ewreg[kt], ea, 0,0,0);
      int cc = w*16 + lm;
      if (cc < NCLS) {
        #pragma unroll
        for (int r = 0; r < 4; ++r)
          emis[((long)prev_t*BATCH + bbase + lg*4 + r)*NCLS + cc] = ea[r];
      }
    }

    // main pipeline: 8 kt-batches, LDS double-buffered, counted vmcnt
    f32x4 acc[16];
    #pragma unroll
    for (int s = 0; s < 16; ++s) acc[s] = (f32x4){0.f,0.f,0.f,0.f};
    #pragma unroll
    for (int kt = 0; kt < 8; ++kt) {
      if (kt < 7) asm volatile("s_waitcnt vmcnt(16)" ::: "memory");
      else        asm volatile("s_waitcnt vmcnt(0)"  ::: "memory");
      __builtin_amdgcn_sched_barrier(0);
      const char* wl = wlds + ((kt & 1) << 14);
      #pragma unroll
      for (int s = 0; s < 16; ++s) {
        s16x8 wf = *(const s16x8*)(wl + (s << 10) + (l << 4));
        acc[s] = __builtin_amdgcn_mfma_f32_16x16x32_bf16(a[kt], wf, acc[s], 0,0,0);
      }
      __builtin_amdgcn_sched_barrier(0);
      if (kt < 6) {
        const char* gsrc = wbase + (((kt + 2) * 16) << 10);
        char* ldst = wlds + ((kt & 1) << 14);
        #pragma unroll
        for (int s = 0; s < 16; ++s)
          gll16(gsrc + (s << 10) + (l << 4), ldst + (s << 10));
      }
    }
    // add xg (loads drained by the kt=0 vmcnt wait)
    #pragma unroll
    for (int qq = 0; qq < 8; ++qq) {
      #pragma unroll
      for (int e = 0; e < 8; ++e) {
        int j = qq*8 + e;
        unsigned wd = xgc[qq][e>>1];
        unsigned short us = (e&1) ? (unsigned short)(wd>>16) : (unsigned short)(wd & 0xffff);
        acc[j>>2][j&3] += bf2f(us);
      }
    }
    // nonlinearities: gates i,f,g,o at s = sub, 4+sub, 8+sub, 12+sub
    unsigned short hnew[16];
    #pragma unroll
    for (int sub = 0; sub < 4; ++sub) {
      #pragma unroll
      for (int r = 0; r < 4; ++r) {
        float gi = acc[sub][r],  gf = acc[4+sub][r];
        float gg = acc[8+sub][r], go = acc[12+sub][r];
        float si = 1.f/(1.f+__expf(-gi));
        float sf = 1.f/(1.f+__expf(-gf));
        float so = 1.f/(1.f+__expf(-go));
        float tg = 2.f/(1.f+__expf(-2.f*gg)) - 1.f;
        float cn = sf*c[sub*4+r] + si*tg;
        c[sub*4+r] = cn;
        float tc = 2.f/(1.f+__expf(-2.f*cn)) - 1.f;
        hnew[sub*4+r] = f2bf(so*tc);
      }
    }
    #pragma unroll
    for (int sub = 0; sub < 4; ++sub) {
      #pragma unroll
      for (int r = 0; r < 4; ++r) {
        int m = lg*4 + r;
        int jc = lm + sub*16 + w*64;
        int off = (m*512 + jc*2) ^ ((m&7)<<4);
        *(unsigned short*)((char*)h_lds + off) = hnew[sub*4+r];
      }
    }
    __syncthreads();
    prev_t = t;
  }

  if (k == NCHUNK-1) {
    // emissions for the final h
    if (w < 2) {
      s16x8 a[8];
      #pragma unroll
      for (int kt = 0; kt < 8; ++kt) {
        int off = lm*512 + ((kt*64 + lg*16) ^ ((lm&7)<<4));
        a[kt] = *(const s16x8*)((const char*)h_lds + off);
      }
      f32x4 ea = {0.f,0.f,0.f,0.f};
      #pragma unroll
      for (int kt = 0; kt < 8; ++kt)
        ea = __builtin_amdgcn_mfma_f32_16x16x32_bf16(a[kt], ewreg[kt], ea, 0,0,0);
      int cc = w*16 + lm;
      if (cc < NCLS) {
        #pragma unroll
        for (int r = 0; r < 4; ++r)
          emis[((long)prev_t*BATCH + bbase + lg*4 + r)*NCLS + cc] = ea[r];
      }
    }
  } else {
    // save state for next chunk
    u32x4* hl = (u32x4*)h_lds;
    u32x4* hs = (u32x4*)(hsave + (long)id*4096);
    for (int i = threadIdx.x; i < 512; i += 256) hs[i] = hl[i];
    float* cs = csave + ((long)id*256 + threadIdx.x)*16;
    #pragma unroll
    for (int i = 0; i < 16; ++i) cs[i] = c[i];
  }
}

// ---------------- CRF numerator -------------------------------------------
__global__ void num_kernel(const int* sent, const int* tags, const float* emis_f,
    const float* emis_b, const float* b_e, const float* start_t, const float* end_t,
    const float* trans, float* num_buf)
{
  int b = blockIdx.x, l = threadIdx.x;   // 64 threads = 1 wave
  float acc = 0.f; int cnt = 0;
  for (int t = l; t < T_LEN; t += 64) {
    int tag = tags[t*BATCH + b];
    float E = emis_f[((long)t*BATCH+b)*NCLS + tag] + emis_b[((long)t*BATCH+b)*NCLS + tag] + b_e[tag];
    int m = (sent[t*BATCH+b] != PADTOK) ? 1 : 0;
    cnt += m;
    if (t == 0) acc += start_t[tag] + E;
    else if (m) acc += trans[tags[(t-1)*BATCH + b]*NCLS + tag] + E;
  }
  #pragma unroll
  for (int off = 32; off; off >>= 1) { acc += __shfl_xor(acc, off); cnt += __shfl_xor(cnt, off); }
  if (l == 0) num_buf[b] = acc + end_t[tags[(cnt-1)*BATCH + b]];
}

// ---------------- CRF forward algorithm (denominator) ----------------------
__global__ void denom_kernel(const int* sent, const float* emis_f, const float* emis_b,
    const float* b_e, const float* start_t, const float* end_t, const float* trans,
    const float* num_buf, float* llh)
{
  __shared__ float tr[NCLS][32];
  __shared__ float sc[2][32];
  __shared__ float be_s[32];
  int l = threadIdx.x, j = l & 31, h = l >> 5;
  int b = blockIdx.x*2 + h;
  for (int i = l; i < NCLS*32; i += 64) { int r = i >> 5, cj = i & 31; tr[r][cj] = (cj<NCLS)? trans[r*NCLS+cj] : 0.f; }
  if (l < 32) be_s[l] = (l < NCLS) ? b_e[l] : 0.f;
  __syncthreads();
  float score = -1e30f;
  if (j < NCLS) score = start_t[j] + emis_f[(long)b*NCLS+j] + emis_b[(long)b*NCLS+j] + be_s[j];
  for (int t = 1; t < T_LEN; ++t) {
    sc[h][j] = score;
    __syncthreads();
    bool m = sent[t*BATCH + b] != PADTOK;
    float mx = -1e30f;
    for (int i = 0; i < NCLS; ++i) mx = fmaxf(mx, sc[h][i] + tr[i][j]);
    float ssum = 0.f;
    for (int i = 0; i < NCLS; ++i) ssum += __expf(sc[h][i] + tr[i][j] - mx);
    float e = (j < NCLS) ? (emis_f[((long)t*BATCH+b)*NCLS+j] + emis_b[((long)t*BATCH+b)*NCLS+j] + be_s[j]) : 0.f;
    float nxt = mx + __logf(ssum) + e;
    if (m && j < NCLS) score = nxt;
    __syncthreads();
  }
  float v = (j < NCLS) ? score + end_t[j] : -1e30f;
  float mx = v;
  #pragma unroll
  for (int off = 16; off; off >>= 1) mx = fmaxf(mx, __shfl_xor(mx, off));
  float ssum = (j < NCLS) ? __expf(v - mx) : 0.f;
  #pragma unroll
  for (int off = 16; off; off >>= 1) ssum += __shfl_xor(ssum, off);
  if (j == 0) llh[b] = num_buf[b] - (mx + __logf(ssum));
}

__global__ void final_kernel(const float* llh, float* out) {
  __shared__ float red[2];
  int l = threadIdx.x;   // 128
  float v = llh[l];
  #pragma unroll
  for (int off = 32; off; off >>= 1) v += __shfl_xor(v, off);
  if ((l & 63) == 0) red[l >> 6] = v;
  __syncthreads();
  if (l == 0) out[0] = -(red[0] + red[1]);
}

extern "C" void kernel_launch(void* const* d_in, const int* in_sizes, int n_in,
                              void* d_out, int out_size, void* d_ws, size_t ws_size,
                              hipStream_t stream) {
  const int*   sent  = (const int*)d_in[0];
  const int*   tags  = (const int*)d_in[1];
  const float* emb   = (const float*)d_in[2];
  const float* wih_f = (const float*)d_in[3];
  const float* whh_f = (const float*)d_in[4];
  const float* bih_f = (const float*)d_in[5];
  const float* bhh_f = (const float*)d_in[6];
  const float* wih_b = (const float*)d_in[7];
  const float* whh_b = (const float*)d_in[8];
  const float* bih_b = (const float*)d_in[9];
  const float* bhh_b = (const float*)d_in[10];
  const float* W_e   = (const float*)d_in[11];
  const float* b_e   = (const float*)d_in[12];
  const float* st    = (const float*)d_in[13];
  const float* et    = (const float*)d_in[14];
  const float* tr    = (const float*)d_in[15];
  (void)in_sizes; (void)n_in; (void)out_size; (void)ws_size;

  char* ws = (char*)d_ws;
  unsigned short* wih_p  = (unsigned short*)ws; ws += (long)N_WPERM*2;      // 1 MiB
  unsigned short* whh_p  = (unsigned short*)ws; ws += (long)N_WPERM*2;      // 1 MiB
  unsigned short* we_p   = (unsigned short*)ws; ws += (long)N_WE*2;         // 32 KiB
  float*          bias   = (float*)ws;          ws += (long)N_BIAS*4;       // 8 KiB
  unsigned short* xgr    = (unsigned short*)ws; ws += (long)2*CHUNK*BATCH*1024*2; // 32 MiB ring
  float*          emis_f = (float*)ws;          ws += (long)T_LEN*BATCH*NCLS*4;   // 6.25 MiB
  float*          emis_b = (float*)ws;          ws += (long)T_LEN*BATCH*NCLS*4;   // 6.25 MiB
  unsigned short* hsave  = (unsigned short*)ws; ws += (long)16*4096*2;      // 128 KiB
  float*          csave  = (float*)ws;          ws += (long)16*256*16*4;    // 256 KiB
  float*          numb   = (float*)ws;          ws += 512;
  float*          llh    = (float*)ws;          ws += 512;
  // total ~47 MiB

  hipFuncSetAttribute(reinterpret_cast<const void*>(lstm_kernel),
                      hipFuncAttributeMaxDynamicSharedMemorySize, LDS_BYTES);

  prep_kernel<<<4168, 256, 0, stream>>>(wih_f, whh_f, bih_f, bhh_f,
                                        wih_b, whh_b, bih_b, bhh_b, W_e,
                                        wih_p, whh_p, we_p, bias);
  for (int k = 0; k < NCHUNK; ++k) {
    dim3 g1(256, 2);
    xg_kernel<<<g1, 256, 0, stream>>>(sent, emb, wih_p, bias, xgr, k);
    lstm_kernel<<<16, 256, LDS_BYTES, stream>>>(xgr, whh_p, we_p, emis_f, emis_b, hsave, csave, k);
  }
  num_kernel<<<128, 64, 0, stream>>>(sent, tags, emis_f, emis_b, b_e, st, et, tr, numb);
  denom_kernel<<<64, 64, 0, stream>>>(sent, emis_f, emis_b, b_e, st, et, tr, numb, llh);
  final_kernel<<<1, 128, 0, stream>>>(llh, (float*)d_out);
}